// Round 1
// baseline (1603.858 us; speedup 1.0000x reference)
//
#include <hip/hip_runtime.h>
#include <hip/hip_fp16.h>

// GCN 2-layer: out = D_in^-1/2 A D_out^-1/2 (relu(D_in^-1/2 A D_out^-1/2 X W1 + b1)) W2 + b2
// Strategy: project-then-aggregate; bucket-partition by dst>>7 (NO within-bucket
// CSR), per-bucket LDS fp32 accumulation in the aggregate.
// R2: register-tiled GEMM. R4: fp16 Y. R7: radix-partition CSR: 368 us.
// R8: dual partition, 354 us.
// R9: bucket-granularity aggregate — deletes bucket_csr/csr_src/row_ptr and the
//     entire src-side partition (hist_s/Ts/sbuf). cnt_out via 1 global int
//     atomic folded into part_hist; cnt_in counted in LDS inside the aggregate.
//     Aggregate is edge-parallel: 8 contiguous gathers in flight per thread for
//     EVERY edge (old per-node kernel processed ~half the edges in a 1-load-
//     in-flight tail loop). LDS acc stride 65 to break even-bank aliasing.

static inline size_t align256(size_t x) { return (x + 255) & ~(size_t)255; }

#define BKT_SHIFT 7
#define BKT_W 128              // nodes per bucket window
#define MAX_NBK 800            // LDS sizing guard (N <= 102400)
#define PA_BLOCKS 416          // partition pass blocks

// A1: per-block bucket histogram of dst>>7 + global out-degree counts.
__global__ __launch_bounds__(256)
void part_hist_kernel(const int* __restrict__ src, const int* __restrict__ dst,
                      int* __restrict__ hist_d, int* __restrict__ cnt_out,
                      int nbk, int E, int slice_len) {
    __shared__ int hd[MAX_NBK];
    const int b = blockIdx.x;
    for (int i = threadIdx.x; i < nbk; i += 256) hd[i] = 0;
    __syncthreads();
    const int beg = b * slice_len;
    const int end = min(beg + slice_len, E);
    for (int i = beg + threadIdx.x; i < end; i += 256) {
        atomicAdd(&hd[dst[i] >> BKT_SHIFT], 1);   // LDS atomic
        atomicAdd(&cnt_out[src[i]], 1);           // global int atomic (deg_out)
    }
    __syncthreads();
    for (int i = threadIdx.x; i < nbk; i += 256)
        hist_d[(size_t)i * PA_BLOCKS + b] = hd[i];
}

// A2: per-bucket-row exclusive prefix over the PA_BLOCKS counts (in place),
// row total out. Grid = nbk blocks.
__global__ __launch_bounds__(512)
void row_scan_kernel(int* __restrict__ hist_d, int* __restrict__ Td, int nbk) {
    __shared__ int tmp[512];
    int* row = hist_d + (size_t)blockIdx.x * PA_BLOCKS;
    const int t = threadIdx.x;
    int v = (t < PA_BLOCKS) ? row[t] : 0;
    tmp[t] = v;
    __syncthreads();
    for (int off = 1; off < 512; off <<= 1) {
        int u = (t >= off) ? tmp[t - off] : 0;
        __syncthreads();
        tmp[t] += u;
        __syncthreads();
    }
    if (t < PA_BLOCKS) row[t] = tmp[t] - v;      // exclusive within row
    if (t == 511) Td[blockIdx.x] = tmp[511];     // row total
}

// A3: exclusive scan of the bucket totals, in place (nbk <= 1024).
__global__ __launch_bounds__(1024)
void tot_scan_kernel(int* __restrict__ Td, int nbk) {
    __shared__ int tmp[1024];
    const int t = threadIdx.x;
    int v = (t < nbk) ? Td[t] : 0;
    tmp[t] = v;
    __syncthreads();
    for (int off = 1; off < 1024; off <<= 1) {
        int u = (t >= off) ? tmp[t - off] : 0;
        __syncthreads();
        tmp[t] += u;
        __syncthreads();
    }
    if (t < nbk) Td[t] = tmp[t] - v;
}

// A4: partition scatter. ebuf gets (dst&127)<<17 | src, bucketed by dst>>7.
__global__ __launch_bounds__(256)
void part_scatter_kernel(const int* __restrict__ src, const int* __restrict__ dst,
                         const int* __restrict__ hist_d, const int* __restrict__ Td,
                         int* __restrict__ ebuf, int nbk, int E, int slice_len) {
    __shared__ int cur_d[MAX_NBK];
    const int b = blockIdx.x;
    for (int i = threadIdx.x; i < nbk; i += 256)
        cur_d[i] = Td[i] + hist_d[(size_t)i * PA_BLOCKS + b];
    __syncthreads();
    const int beg = b * slice_len;
    const int end = min(beg + slice_len, E);
    for (int i = beg + threadIdx.x; i < end; i += 256) {
        int d = dst[i], s = src[i];
        int pd = atomicAdd(&cur_d[d >> BKT_SHIFT], 1);   // LDS atomic
        ebuf[pd] = ((d & (BKT_W - 1)) << 17) | s;
    }
}

// Y[n][j] = (sum_k X[n][k] * W[k][j]) * rsqrt(max(cnt_out[n],1)), stored fp16.
template <int K>
__global__ __launch_bounds__(256)
void gemm_scale_kernel(const float* __restrict__ X, const float* __restrict__ W,
                       const int* __restrict__ cnt_out,
                       __half* __restrict__ Y, int N) {
    __shared__ float Ws[K][64];
    const int t = threadIdx.x;
    for (int i = t; i < K * 64; i += 256) Ws[i >> 6][i & 63] = W[i];
    __syncthreads();

    const int cid = t & 15;
    const int rid = t >> 4;
    const int rowBase = blockIdx.x * 64;

    const float* xp[4];
    int r[4];
#pragma unroll
    for (int i = 0; i < 4; ++i) {
        r[i] = rowBase + 4 * rid + i;
        xp[i] = X + (size_t)min(r[i], N - 1) * K;
    }

    float acc[4][4] = {};
#pragma unroll 2
    for (int kq = 0; kq < K / 4; ++kq) {
        const int k = kq * 4;
        float4 xv[4], wv[4];
#pragma unroll
        for (int i = 0; i < 4; ++i) xv[i] = *(const float4*)(xp[i] + k);
#pragma unroll
        for (int tt = 0; tt < 4; ++tt) wv[tt] = *(const float4*)&Ws[k + tt][4 * cid];
#pragma unroll
        for (int i = 0; i < 4; ++i) {
            const float* xf = (const float*)&xv[i];
#pragma unroll
            for (int tt = 0; tt < 4; ++tt) {
                const float a = xf[tt];
                const float* wf = (const float*)&wv[tt];
                acc[i][0] += a * wf[0];
                acc[i][1] += a * wf[1];
                acc[i][2] += a * wf[2];
                acc[i][3] += a * wf[3];
            }
        }
    }

#pragma unroll
    for (int i = 0; i < 4; ++i) {
        if (r[i] < N) {
            float sc = rsqrtf((float)max(cnt_out[r[i]], 1));
            __half2* yp = (__half2*)&Y[(size_t)r[i] * 64 + 4 * cid];
            yp[0] = __halves2half2(__float2half_rn(acc[i][0] * sc),
                                   __float2half_rn(acc[i][1] * sc));
            yp[1] = __halves2half2(__float2half_rn(acc[i][2] * sc),
                                   __float2half_rn(acc[i][3] * sc));
        }
    }
}

// B: per-bucket aggregate. Block = 1 bucket (128 dst nodes), 512 threads =
// 16 edge-slots x 32 feature-pairs. LDS fp32 accumulator, stride 65 floats
// (breaks the d*64+2f even-bank pattern; ~2-way = free). Each thread streams
// 8 CONTIGUOUS edges per iteration (8 gathers in flight for every edge —
// no 1-load tail loop), clamped+masked at the bucket end. in-degree counted
// in LDS by the f==0 lane of each slot.
template <bool RELU>
__global__ __launch_bounds__(512)
void agg_bucket_kernel(const __half* __restrict__ Y,
                       const int* __restrict__ ebuf,
                       const int* __restrict__ Td,
                       const float* __restrict__ bias,
                       float* __restrict__ out,
                       int nbk, int N, int E) {
    __shared__ float acc[BKT_W * 65];
    __shared__ int cnt[BKT_W];
    const int t = threadIdx.x;
    const int slot = t >> 5;       // 0..15
    const int f = t & 31;          // half2 feature index (features 2f, 2f+1)
    const int k = blockIdx.x;
    const int lo = k << BKT_SHIFT;
    const int span = min(BKT_W, N - lo);
    const int db = Td[k];
    const int de = (k + 1 < nbk) ? Td[k + 1] : E;

    for (int i = t; i < BKT_W * 65; i += 512) acc[i] = 0.f;
    if (t < BKT_W) cnt[t] = 0;
    __syncthreads();

    const int last = de - 1;
    for (int base = db + slot * 8; base < de; base += 128) {
        int p[8];
#pragma unroll
        for (int j = 0; j < 8; ++j) p[j] = ebuf[min(base + j, last)];
        float2 v[8];
#pragma unroll
        for (int j = 0; j < 8; ++j)
            v[j] = __half22float2(
                *((const __half2*)(Y + ((size_t)(p[j] & 0x1FFFF) << 6)) + f));
#pragma unroll
        for (int j = 0; j < 8; ++j) {
            if (base + j <= last) {
                float* a = &acc[(p[j] >> 17) * 65 + 2 * f];
                atomicAdd(a, v[j].x);          // ds_add_f32
                atomicAdd(a + 1, v[j].y);
                if (f == 0) atomicAdd(&cnt[p[j] >> 17], 1);
            }
        }
    }
    __syncthreads();

    for (int i = t; i < span * 64; i += 512) {
        const int n = i >> 6, ff = i & 63;
        float sc = rsqrtf((float)max(cnt[n], 1));
        float o = acc[n * 65 + ff] * sc + bias[ff];
        if (RELU) o = fmaxf(o, 0.f);
        out[((size_t)(lo + n) << 6) + ff] = o;
    }
}

extern "C" void kernel_launch(void* const* d_in, const int* in_sizes, int n_in,
                              void* d_out, int out_size, void* d_ws, size_t ws_size,
                              hipStream_t stream) {
    const float* x   = (const float*)d_in[0];
    const int*   src = (const int*)d_in[1];
    const int*   dst = (const int*)d_in[2];
    const float* W1  = (const float*)d_in[3];
    const float* b1  = (const float*)d_in[4];
    const float* W2  = (const float*)d_in[5];
    const float* b2  = (const float*)d_in[6];
    float* out = (float*)d_out;

    const int N = in_sizes[0] / 128;   // 100000
    const int E = in_sizes[1];         // 1600000

    const int nbk = (N + BKT_W - 1) >> BKT_SHIFT;          // 782 buckets
    const int M = nbk * PA_BLOCKS;

    // Workspace (~21 MB). d_out doubles as the hidden-layer buffer.
    char* ws = (char*)d_ws;
    size_t off = 0;
    __half* Y       = (__half*)(ws + off); off = align256(off + (size_t)N * 64 * sizeof(__half));
    int* ebuf       = (int*)(ws + off);    off = align256(off + (size_t)E * sizeof(int));
    int* hist_d     = (int*)(ws + off);    off = align256(off + (size_t)M * sizeof(int));
    int* Td         = (int*)(ws + off);    off = align256(off + (size_t)nbk * sizeof(int));
    int* cnt_out    = (int*)(ws + off);    off = align256(off + (size_t)N * sizeof(int));

    const int pslice = (E + PA_BLOCKS - 1) / PA_BLOCKS;

    // Bucket partition + degree counts
    hipMemsetAsync(cnt_out, 0, (size_t)N * sizeof(int), stream);
    part_hist_kernel<<<PA_BLOCKS, 256, 0, stream>>>(src, dst, hist_d, cnt_out, nbk, E, pslice);
    row_scan_kernel<<<nbk, 512, 0, stream>>>(hist_d, Td, nbk);
    tot_scan_kernel<<<1, 1024, 0, stream>>>(Td, nbk);
    part_scatter_kernel<<<PA_BLOCKS, 256, 0, stream>>>(src, dst, hist_d, Td, ebuf, nbk, E, pslice);

    const int gemm_blocks = (N + 63) / 64;

    // Layer 1: Y = fp16[(X @ W1) * rs_out] ; bucket-agg -> d_out (hidden, relu)
    gemm_scale_kernel<128><<<gemm_blocks, 256, 0, stream>>>(x, W1, cnt_out, Y, N);
    agg_bucket_kernel<true><<<nbk, 512, 0, stream>>>(Y, ebuf, Td, b1, out, nbk, N, E);

    // Layer 2: Y = fp16[(H @ W2) * rs_out] ; bucket-agg -> d_out (final)
    gemm_scale_kernel<64><<<gemm_blocks, 256, 0, stream>>>(out, W2, cnt_out, Y, N);
    agg_bucket_kernel<false><<<nbk, 512, 0, stream>>>(Y, ebuf, Td, b2, out, nbk, N, E);
}

// Round 2
// 302.136 us; speedup vs baseline: 5.3084x; 5.3084x over previous
//
#include <hip/hip_runtime.h>
#include <hip/hip_fp16.h>

// GCN 2-layer: out = D_in^-1/2 A D_out^-1/2 (relu(D_in^-1/2 A D_out^-1/2 X W1 + b1)) W2 + b2
// Strategy: project-then-aggregate; CSR-by-dst via radix partition, zero
// device-scope atomics anywhere.
// R2: register-tiled GEMM. R4: fp16 Y. R6: atomic-rank floor = 67us.
// R7: radix-partition CSR (dst>>7 buckets, LDS cursors). 368 us.
// R8: DUAL partition (cnt_out from 1-byte sbuf), 354 us.
// R9 FAILED (1604 us): per-bucket LDS fp32 atomicAdd aggregate -> CAS-loop
//     serialization (VALUBusy 2.9%). Lesson: no fp atomics in hot path.
// R10: revert to R8 pipeline; aggregate tail fix — half-wave per node,
//     clamped unroll-8 edge loop so EVERY row runs with 8 gathers in flight
//     (R8 processed ~45% of edges in a 1-load-in-flight tail loop).

static inline size_t align256(size_t x) { return (x + 255) & ~(size_t)255; }

#define BKT_SHIFT 7
#define BKT_W 128              // nodes per bucket window
#define MAX_NBK 800            // LDS sizing guard (N <= 102400)
#define PA_BLOCKS 416          // partition pass blocks

// A1: per-block bucket histograms of BOTH dst>>7 and src>>7.
__global__ __launch_bounds__(256)
void part_hist_kernel(const int* __restrict__ src, const int* __restrict__ dst,
                      int* __restrict__ hist_d, int* __restrict__ hist_s,
                      int nbk, int E, int slice_len) {
    __shared__ int hd[MAX_NBK];
    __shared__ int hs[MAX_NBK];
    const int b = blockIdx.x;
    for (int i = threadIdx.x; i < nbk; i += 256) { hd[i] = 0; hs[i] = 0; }
    __syncthreads();
    const int beg = b * slice_len;
    const int end = min(beg + slice_len, E);
    for (int i = beg + threadIdx.x; i < end; i += 256) {
        atomicAdd(&hd[dst[i] >> BKT_SHIFT], 1);   // LDS atomics (int: native)
        atomicAdd(&hs[src[i] >> BKT_SHIFT], 1);
    }
    __syncthreads();
    for (int i = threadIdx.x; i < nbk; i += 256) {
        hist_d[(size_t)i * PA_BLOCKS + b] = hd[i];
        hist_s[(size_t)i * PA_BLOCKS + b] = hs[i];
    }
}

// A2: per-bucket-row exclusive prefix over the PA_BLOCKS counts (in place),
// row total out. Grid = 2*nbk blocks (dst rows then src rows).
__global__ __launch_bounds__(512)
void row_scan_kernel(int* __restrict__ hist_d, int* __restrict__ hist_s,
                     int* __restrict__ Td, int* __restrict__ Ts, int nbk) {
    __shared__ int tmp[512];
    int j = blockIdx.x;
    int* row;
    int* T;
    if (j < nbk) { row = hist_d + (size_t)j * PA_BLOCKS; T = Td; }
    else         { j -= nbk; row = hist_s + (size_t)j * PA_BLOCKS; T = Ts; }
    const int t = threadIdx.x;
    int v = (t < PA_BLOCKS) ? row[t] : 0;
    tmp[t] = v;
    __syncthreads();
    for (int off = 1; off < 512; off <<= 1) {
        int u = (t >= off) ? tmp[t - off] : 0;
        __syncthreads();
        tmp[t] += u;
        __syncthreads();
    }
    if (t < PA_BLOCKS) row[t] = tmp[t] - v;      // exclusive within row
    if (t == 511) T[j] = tmp[511];               // row total
}

// A3: exclusive scan of the bucket totals (both tables), in place.
__global__ __launch_bounds__(1024)
void tot_scan_kernel(int* __restrict__ Td, int* __restrict__ Ts, int nbk) {
    __shared__ int tmp[1024];
    const int t = threadIdx.x;
    int v = (t < nbk) ? Td[t] : 0;
    tmp[t] = v;
    __syncthreads();
    for (int off = 1; off < 1024; off <<= 1) {
        int u = (t >= off) ? tmp[t - off] : 0;
        __syncthreads();
        tmp[t] += u;
        __syncthreads();
    }
    if (t < nbk) Td[t] = tmp[t] - v;
    __syncthreads();
    int v2 = (t < nbk) ? Ts[t] : 0;
    tmp[t] = v2;
    __syncthreads();
    for (int off = 1; off < 1024; off <<= 1) {
        int u = (t >= off) ? tmp[t - off] : 0;
        __syncthreads();
        tmp[t] += u;
        __syncthreads();
    }
    if (t < nbk) Ts[t] = tmp[t] - v2;
}

// A4: partition scatter. ebuf gets (dst&127)<<17 | src (dst-bucketed);
// sbuf gets 1-byte src&127 (src-bucketed) for the cnt_out count.
__global__ __launch_bounds__(256)
void part_scatter_kernel(const int* __restrict__ src, const int* __restrict__ dst,
                         const int* __restrict__ hist_d, const int* __restrict__ hist_s,
                         const int* __restrict__ Td, const int* __restrict__ Ts,
                         int* __restrict__ ebuf, unsigned char* __restrict__ sbuf,
                         int nbk, int E, int slice_len) {
    __shared__ int cur_d[MAX_NBK];
    __shared__ int cur_s[MAX_NBK];
    const int b = blockIdx.x;
    for (int i = threadIdx.x; i < nbk; i += 256) {
        cur_d[i] = Td[i] + hist_d[(size_t)i * PA_BLOCKS + b];
        cur_s[i] = Ts[i] + hist_s[(size_t)i * PA_BLOCKS + b];
    }
    __syncthreads();
    const int beg = b * slice_len;
    const int end = min(beg + slice_len, E);
    for (int i = beg + threadIdx.x; i < end; i += 256) {
        int d = dst[i], s = src[i];
        int pd = atomicAdd(&cur_d[d >> BKT_SHIFT], 1);   // LDS atomic
        ebuf[pd] = ((d & (BKT_W - 1)) << 17) | s;
        int ps = atomicAdd(&cur_s[s >> BKT_SHIFT], 1);   // LDS atomic
        sbuf[ps] = (unsigned char)(s & (BKT_W - 1));
    }
}

// B: per-bucket finalize. Emits cnt_in, cnt_out, row_ptr, csr_src.
__global__ __launch_bounds__(256)
void bucket_csr_kernel(const int* __restrict__ ebuf,
                       const unsigned char* __restrict__ sbuf,
                       const int* __restrict__ Td, const int* __restrict__ Ts,
                       int* __restrict__ csr_src,
                       int* __restrict__ cnt_in, int* __restrict__ cnt_out,
                       int* __restrict__ row_ptr,
                       int nbk, int N, int E) {
    __shared__ int cnt[BKT_W];
    __shared__ int rp[BKT_W];
    __shared__ int cur[BKT_W];
    __shared__ int cnts[BKT_W];
    const int k = blockIdx.x;
    const int lo = k << BKT_SHIFT;
    const int span = min(BKT_W, N - lo);
    const int db = Td[k], de = (k + 1 < nbk) ? Td[k + 1] : E;
    const int sb = Ts[k], se = (k + 1 < nbk) ? Ts[k + 1] : E;
    const int t = threadIdx.x;

    if (t < BKT_W) { cnt[t] = 0; cnts[t] = 0; }
    __syncthreads();
    for (int i = db + t; i < de; i += 256) atomicAdd(&cnt[ebuf[i] >> 17], 1);
    for (int i = sb + t; i < se; i += 256) atomicAdd(&cnts[sbuf[i]], 1);
    __syncthreads();
    if (t < BKT_W) rp[t] = cnt[t];
    __syncthreads();
    for (int off = 1; off < BKT_W; off <<= 1) {
        int v = (t < BKT_W && t >= off) ? rp[t - off] : 0;
        __syncthreads();
        if (t < BKT_W) rp[t] += v;
        __syncthreads();
    }
    if (t < span) {
        row_ptr[lo + t] = db + rp[t] - cnt[t];
        cnt_in[lo + t]  = cnt[t];
        cnt_out[lo + t] = cnts[t];
    }
    __syncthreads();
    if (t < BKT_W) cur[t] = db + rp[t] - cnt[t];
    __syncthreads();
    for (int i = db + t; i < de; i += 256) {
        int p = ebuf[i];
        int pos = atomicAdd(&cur[p >> 17], 1);           // LDS atomic
        csr_src[pos] = p & 0x1FFFF;
    }
    if (k == 0 && t == 0) row_ptr[N] = E;
}

// Y[n][j] = (sum_k X[n][k] * W[k][j]) * rsqrt(max(cnt_out[n],1)), stored fp16.
template <int K>
__global__ __launch_bounds__(256)
void gemm_scale_kernel(const float* __restrict__ X, const float* __restrict__ W,
                       const int* __restrict__ cnt_out,
                       __half* __restrict__ Y, int N) {
    __shared__ float Ws[K][64];
    const int t = threadIdx.x;
    for (int i = t; i < K * 64; i += 256) Ws[i >> 6][i & 63] = W[i];
    __syncthreads();

    const int cid = t & 15;
    const int rid = t >> 4;
    const int rowBase = blockIdx.x * 64;

    const float* xp[4];
    int r[4];
#pragma unroll
    for (int i = 0; i < 4; ++i) {
        r[i] = rowBase + 4 * rid + i;
        xp[i] = X + (size_t)min(r[i], N - 1) * K;
    }

    float acc[4][4] = {};
#pragma unroll 2
    for (int kq = 0; kq < K / 4; ++kq) {
        const int k = kq * 4;
        float4 xv[4], wv[4];
#pragma unroll
        for (int i = 0; i < 4; ++i) xv[i] = *(const float4*)(xp[i] + k);
#pragma unroll
        for (int tt = 0; tt < 4; ++tt) wv[tt] = *(const float4*)&Ws[k + tt][4 * cid];
#pragma unroll
        for (int i = 0; i < 4; ++i) {
            const float* xf = (const float*)&xv[i];
#pragma unroll
            for (int tt = 0; tt < 4; ++tt) {
                const float a = xf[tt];
                const float* wf = (const float*)&wv[tt];
                acc[i][0] += a * wf[0];
                acc[i][1] += a * wf[1];
                acc[i][2] += a * wf[2];
                acc[i][3] += a * wf[3];
            }
        }
    }

#pragma unroll
    for (int i = 0; i < 4; ++i) {
        if (r[i] < N) {
            float sc = rsqrtf((float)max(cnt_out[r[i]], 1));
            __half2* yp = (__half2*)&Y[(size_t)r[i] * 64 + 4 * cid];
            yp[0] = __halves2half2(__float2half_rn(acc[i][0] * sc),
                                   __float2half_rn(acc[i][1] * sc));
            yp[1] = __halves2half2(__float2half_rn(acc[i][2] * sc),
                                   __float2half_rn(acc[i][3] * sc));
        }
    }
}

// out[n][f] = (sum_{in-edges} Y[src][f]) * rsqrt(max(cnt_in[n],1)) + bias[f]
// Half-wave (32 lanes) per node; lane = one half2 feature pair.
// Clamped unroll-8 edge loop: indices min(e+j, end-1), masked accumulate —
// EVERY row (not just deg>=16 ones) runs with 8 gathers in flight per lane.
// No atomics, no shuffles; each lane exclusively owns (node, feature-pair).
template <bool RELU>
__global__ __launch_bounds__(256)
void aggregate_kernel(const __half* __restrict__ Y,
                      const int* __restrict__ row_ptr,
                      const int* __restrict__ csr_src,
                      const int* __restrict__ cnt_in,
                      const float* __restrict__ bias,
                      float* __restrict__ out, int N) {
    const int n = blockIdx.x * 8 + (threadIdx.x >> 5);
    if (n >= N) return;
    const int fp = threadIdx.x & 31;          // features 2*fp, 2*fp+1

    const int start = row_ptr[n];
    const int end   = row_ptr[n + 1];
    const int last  = end - 1;

    float2 acc = {0.f, 0.f};
    for (int e = start; e < end; e += 8) {
        int idx[8];
#pragma unroll
        for (int j = 0; j < 8; ++j) idx[j] = csr_src[min(e + j, last)];
        float2 v[8];
#pragma unroll
        for (int j = 0; j < 8; ++j)
            v[j] = __half22float2(*((const __half2*)(Y + ((size_t)idx[j] << 6)) + fp));
#pragma unroll
        for (int j = 0; j < 8; ++j)
            if (e + j < end) { acc.x += v[j].x; acc.y += v[j].y; }
    }

    const float sc = rsqrtf((float)max(cnt_in[n], 1));
    float2 o;
    o.x = acc.x * sc + bias[2 * fp];
    o.y = acc.y * sc + bias[2 * fp + 1];
    if (RELU) { o.x = fmaxf(o.x, 0.f); o.y = fmaxf(o.y, 0.f); }
    *(float2*)&out[((size_t)n << 6) + 2 * fp] = o;
}

extern "C" void kernel_launch(void* const* d_in, const int* in_sizes, int n_in,
                              void* d_out, int out_size, void* d_ws, size_t ws_size,
                              hipStream_t stream) {
    const float* x   = (const float*)d_in[0];
    const int*   src = (const int*)d_in[1];
    const int*   dst = (const int*)d_in[2];
    const float* W1  = (const float*)d_in[3];
    const float* b1  = (const float*)d_in[4];
    const float* W2  = (const float*)d_in[5];
    const float* b2  = (const float*)d_in[6];
    float* out = (float*)d_out;

    const int N = in_sizes[0] / 128;   // 100000
    const int E = in_sizes[1];         // 1600000

    const int nbk = (N + BKT_W - 1) >> BKT_SHIFT;          // 782 buckets
    const int M = nbk * PA_BLOCKS;

    // Workspace (~30 MB). d_out doubles as the hidden-layer buffer.
    char* ws = (char*)d_ws;
    size_t off = 0;
    __half* Y       = (__half*)(ws + off); off = align256(off + (size_t)N * 64 * sizeof(__half));
    int* csr_src    = (int*)(ws + off);    off = align256(off + (size_t)E * sizeof(int));
    int* ebuf       = (int*)(ws + off);    off = align256(off + (size_t)E * sizeof(int));
    unsigned char* sbuf = (unsigned char*)(ws + off); off = align256(off + (size_t)E);
    int* hist_d     = (int*)(ws + off);    off = align256(off + (size_t)M * sizeof(int));
    int* hist_s     = (int*)(ws + off);    off = align256(off + (size_t)M * sizeof(int));
    int* Td         = (int*)(ws + off);    off = align256(off + (size_t)nbk * sizeof(int));
    int* Ts         = (int*)(ws + off);    off = align256(off + (size_t)nbk * sizeof(int));
    int* cnt_out    = (int*)(ws + off);    off = align256(off + (size_t)N * sizeof(int));
    int* cnt_in     = (int*)(ws + off);    off = align256(off + (size_t)N * sizeof(int));
    int* row_ptr    = (int*)(ws + off);    off = align256(off + (size_t)(N + 1) * sizeof(int));

    const int pslice = (E + PA_BLOCKS - 1) / PA_BLOCKS;

    // Dual radix-partition CSR build + degree counts (zero device atomics)
    part_hist_kernel<<<PA_BLOCKS, 256, 0, stream>>>(src, dst, hist_d, hist_s, nbk, E, pslice);
    row_scan_kernel<<<2 * nbk, 512, 0, stream>>>(hist_d, hist_s, Td, Ts, nbk);
    tot_scan_kernel<<<1, 1024, 0, stream>>>(Td, Ts, nbk);
    part_scatter_kernel<<<PA_BLOCKS, 256, 0, stream>>>(src, dst, hist_d, hist_s, Td, Ts,
                                                       ebuf, sbuf, nbk, E, pslice);
    bucket_csr_kernel<<<nbk, 256, 0, stream>>>(ebuf, sbuf, Td, Ts, csr_src,
                                               cnt_in, cnt_out, row_ptr, nbk, N, E);

    const int gemm_blocks = (N + 63) / 64;
    const int agg_blocks  = (N + 7) / 8;

    // Layer 1: Y = fp16[(X @ W1) * rs_out] ; agg -> d_out (hidden, relu)
    gemm_scale_kernel<128><<<gemm_blocks, 256, 0, stream>>>(x, W1, cnt_out, Y, N);
    aggregate_kernel<true><<<agg_blocks, 256, 0, stream>>>(Y, row_ptr, csr_src, cnt_in, b1, out, N);

    // Layer 2: Y = fp16[(H @ W2) * rs_out] ; agg -> d_out (final)
    gemm_scale_kernel<64><<<gemm_blocks, 256, 0, stream>>>(out, W2, cnt_out, Y, N);
    aggregate_kernel<false><<<agg_blocks, 256, 0, stream>>>(Y, row_ptr, csr_src, cnt_in, b2, out, N);
}